// Round 17
// baseline (94.512 us; speedup 1.0000x reference)
//
#include <hip/hip_runtime.h>
#include <hip/hip_fp16.h>

#define D_FEAT 128
#define SHIFT 7          // nodes per bucket = 128
#define NPB   128        // nodes per bucket
#define CAPB  3072       // bucket capacity (mean ~2046, sigma ~45 -> +22 sigma)
#define NBMAX 512        // max buckets supported by phase-A LDS arrays
#define EPT   8          // edges per thread in phase A
#define CAST_BLOCKS 1536

// ---------------- fast path: LDS-bucketed scatter + in-LDS CSR + sliced fp16 gather -------
// hbt layout: 4 planes of [n_nodes][32] halfs (plane p = features 32p..32p+31).
// Gather makes 4 passes over the LDS edge list; each pass touches a 3.2MB dense
// plane -> per-XCD L2-resident -> 16x row reuse becomes L2 hits.

// Phase A (fused): fill role buckets edges via LDS aggregation (NB up to 512);
// cast role streams h -> sliced fp16 planes + exact f32 copy into out[:,0:128].
__global__ void __launch_bounds__(256) fused_cast_bucket_kernel(
    const float* __restrict__ h, __half* __restrict__ hbt,
    float* __restrict__ out, int n_elems, int n_nodes,
    const float* __restrict__ w, const int* __restrict__ src,
    const int* __restrict__ dst,
    int* __restrict__ bcur, int2* __restrict__ buck, int n_edges,
    int fill_blocks, int nb)
{
    __shared__ int lcnt[NBMAX];
    __shared__ int lbase[NBMAX];
    __shared__ int lpos[NBMAX];
    if ((int)blockIdx.x < fill_blocks) {
        const int t  = threadIdx.x;
        const int cb = blockIdx.x * (256 * EPT);
        for (int bb = t; bb < NBMAX; bb += 256) { lcnt[bb] = 0; lpos[bb] = 0; }
        __syncthreads();
        int ed[EPT], es[EPT]; float ew[EPT];
#pragma unroll
        for (int j = 0; j < EPT; ++j) {
            const int e = cb + j * 256 + t;
            if (e < n_edges) {
                ed[j] = dst[e]; es[j] = src[e]; ew[j] = w[e];
                atomicAdd(&lcnt[ed[j] >> SHIFT], 1);
            } else ed[j] = -1;
        }
        __syncthreads();
        for (int bb = t; bb < nb; bb += 256) {
            const int c = lcnt[bb];
            lbase[bb] = c ? atomicAdd(&bcur[bb], c) : 0;
        }
        __syncthreads();
#pragma unroll
        for (int j = 0; j < EPT; ++j) {
            if (ed[j] >= 0) {
                const int b   = ed[j] >> SHIFT;
                const unsigned lid = (unsigned)(ed[j] & (NPB - 1));
                const int p   = atomicAdd(&lpos[b], 1);
                const int gp  = lbase[b] + p;
                if (gp < CAPB)   // +22 sigma; statistically impossible, guard anyway
                    buck[(size_t)b * CAPB + gp] =
                        make_int2((int)((lid << 24) | (unsigned)es[j]), __float_as_int(ew[j]));
            }
        }
    } else {
        const int t      = (blockIdx.x - fill_blocks) * 256 + threadIdx.x;
        const int stride = CAST_BLOCKS * 256;
        const int n4     = n_elems >> 2;
        for (int i = t; i < n4; i += stride) {
            const float4 v = ((const float4*)h)[i];
            const int n = i >> 5;                  // node
            const int q = i & 31;                  // feature quad (features 4q..4q+3)
            const int p = q >> 3;                  // plane
            const int fo = (q & 7) << 1;           // half2 offset within 16-half2 slice
            __half2* hp = (__half2*)hbt + ((size_t)p * n_nodes + n) * 16 + fo;
            hp[0] = __float22half2_rn(make_float2(v.x, v.y));
            hp[1] = __float22half2_rn(make_float2(v.z, v.w));
            ((float4*)(out + (size_t)n * 2 * D_FEAT))[q] = v;   // cols 0..127
        }
    }
}

// Merged phase B + gather: one 1024-thread block per bucket (~50KB LDS ->
// 2 blocks/CU). Stage + count/scan/permute in LDS, then 4 feature-plane passes
// over the LDS edge list: lane-group g (16 lanes) takes edges k+4j+g,
// shfl_xor-reduce across groups, group 0 stores the 128B out slice.
__global__ void __launch_bounds__(1024) bucket_gather_kernel(
    const int* __restrict__ bcur, const int2* __restrict__ buck,
    const __half* __restrict__ hbt, float* __restrict__ out, int n_nodes)
{
    __shared__ int2 ebuf[CAPB];    // 24KB raw bucket edges
    __shared__ int2 ebuf2[CAPB];   // 24KB node-ordered edges
    __shared__ int  ncnt[NPB];
    __shared__ int  sst[NPB];
    __shared__ int  ncur[NPB];
    const int b = blockIdx.x;
    const int t = threadIdx.x;
    const size_t base = (size_t)b * CAPB;
    int cnt = bcur[b]; if (cnt > CAPB) cnt = CAPB;

    if (t < NPB) ncnt[t] = 0;
    __syncthreads();
    for (int i = t; i < cnt; i += 1024) {
        const int2 e = buck[base + i];
        ebuf[i] = e;
        atomicAdd(&ncnt[((unsigned)e.x) >> 24], 1);
    }
    __syncthreads();
    int v = 0;
    if (t < NPB) { v = ncnt[t]; sst[t] = v; }
    __syncthreads();
    for (int o = 1; o < NPB; o <<= 1) {
        int x = 0;
        if (t < NPB && t >= o) x = sst[t - o];
        __syncthreads();
        if (t < NPB) sst[t] += x;
        __syncthreads();
    }
    if (t < NPB) { const int st = sst[t] - v; sst[t] = st; ncur[t] = st; }
    __syncthreads();
    for (int i = t; i < cnt; i += 1024) {
        const int2 e = ebuf[i];
        const unsigned ex = (unsigned)e.x;
        const int lid = (int)(ex >> 24);
        const int p = atomicAdd(&ncur[lid], 1);
        ebuf2[p] = make_int2((int)(ex & 0xFFFFFFu), e.y);
    }
    __syncthreads();

    const int lane = t & 63;
    const int wv   = t >> 6;
    const int g    = lane >> 4;    // edge group 0..3
    const int fl   = lane & 15;    // half2 index within the 32-feature slice

    for (int p = 0; p < 4; ++p) {
        const __half2* __restrict__ hp = (const __half2*)hbt + (size_t)p * n_nodes * 16;
        for (int ln = wv; ln < NPB; ln += 16) {
            const int n = b * NPB + ln;
            if (n >= n_nodes) continue;
            const int st = sst[ln];
            const int c  = ncnt[ln];
            float2 acc = make_float2(0.f, 0.f);
            for (int k = 0; k < c; k += 16) {
                const int j0 = k + g, j1 = k + 4 + g, j2 = k + 8 + g, j3 = k + 12 + g;
                const int2 e0 = ebuf2[st + (j0 < c ? j0 : 0)];
                const int2 e1 = ebuf2[st + (j1 < c ? j1 : 0)];
                const int2 e2 = ebuf2[st + (j2 < c ? j2 : 0)];
                const int2 e3 = ebuf2[st + (j3 < c ? j3 : 0)];
                const float w0 = j0 < c ? __int_as_float(e0.y) : 0.f;
                const float w1 = j1 < c ? __int_as_float(e1.y) : 0.f;
                const float w2 = j2 < c ? __int_as_float(e2.y) : 0.f;
                const float w3 = j3 < c ? __int_as_float(e3.y) : 0.f;
                const float2 h0 = __half22float2(hp[(size_t)e0.x * 16 + fl]);
                const float2 h1 = __half22float2(hp[(size_t)e1.x * 16 + fl]);
                const float2 h2 = __half22float2(hp[(size_t)e2.x * 16 + fl]);
                const float2 h3 = __half22float2(hp[(size_t)e3.x * 16 + fl]);
                acc.x = fmaf(h0.x, w0, acc.x); acc.y = fmaf(h0.y, w0, acc.y);
                acc.x = fmaf(h1.x, w1, acc.x); acc.y = fmaf(h1.y, w1, acc.y);
                acc.x = fmaf(h2.x, w2, acc.x); acc.y = fmaf(h2.y, w2, acc.y);
                acc.x = fmaf(h3.x, w3, acc.x); acc.y = fmaf(h3.y, w3, acc.y);
            }
            acc.x += __shfl_xor(acc.x, 16, 64);
            acc.y += __shfl_xor(acc.y, 16, 64);
            acc.x += __shfl_xor(acc.x, 32, 64);
            acc.y += __shfl_xor(acc.y, 32, 64);
            if (g == 0) {
                const float inv = 1.0f / fmaxf((float)c, 1.0f);
                float2* op = (float2*)(out + (size_t)n * 2 * D_FEAT + D_FEAT + p * 32) + fl;
                *op = make_float2(acc.x * inv, acc.y * inv);
            }
        }
    }
}

// ---------------- tier-2 path (round-12 measured: fused cast+fill, CAP bins) ----------------

#define CAP 32
#define T2_CAST_BLOCKS 512
#define T2_FILL_BLOCKS 2048

__global__ void __launch_bounds__(256) fused_cast_fill_kernel(
    const float* __restrict__ h, __half* __restrict__ hb,
    float* __restrict__ out, int n_elems,
    const float* __restrict__ w, const int* __restrict__ src,
    const int* __restrict__ dst,
    int* __restrict__ count, int* __restrict__ ovf_count,
    int* __restrict__ ovf_list, int2* __restrict__ bins, int n_edges)
{
    if (blockIdx.x < T2_CAST_BLOCKS) {
        const int t      = blockIdx.x * blockDim.x + threadIdx.x;
        const int stride = T2_CAST_BLOCKS * blockDim.x;
        const int n4     = n_elems >> 2;
        for (int i = t; i < n4; i += stride) {
            const float4 v = ((const float4*)h)[i];
            ((__half2*)hb)[2 * i]     = __float22half2_rn(make_float2(v.x, v.y));
            ((__half2*)hb)[2 * i + 1] = __float22half2_rn(make_float2(v.z, v.w));
            const int n = i >> 5;
            const int q = i & 31;
            ((float4*)(out + (size_t)n * 2 * D_FEAT))[q] = v;
        }
    } else {
        const int t      = (blockIdx.x - T2_CAST_BLOCKS) * blockDim.x + threadIdx.x;
        const int stride = T2_FILL_BLOCKS * blockDim.x;
        for (int e = t; e < n_edges; e += stride) {
            const int d = dst[e];
            const int pos = atomicAdd(&count[d], 1);
            if (pos < CAP) {
                bins[(size_t)d * CAP + pos] = make_int2(src[e], __float_as_int(w[e]));
            } else {
                const int o = atomicAdd(ovf_count, 1);
                ovf_list[o] = e;
            }
        }
    }
}

__global__ void __launch_bounds__(256) t2_gather_kernel(
    const __half* __restrict__ hb, const int* __restrict__ count,
    const int2* __restrict__ bins, float* __restrict__ out, int n_nodes)
{
    const int lane = threadIdx.x & 63;
    const int wave = (blockIdx.x * blockDim.x + threadIdx.x) >> 6;
    if (wave >= n_nodes) return;
    const int n   = wave;
    const int cnt = count[n];
    const int c   = cnt < CAP ? cnt : CAP;
    float2 acc = make_float2(0.0f, 0.0f);
    const int2* bp = bins + (size_t)n * CAP;
    for (int k = 0; k < c; ++k) {
        const int2 b = bp[k];
        const float2 hv = __half22float2(((const __half2*)(hb + (size_t)b.x * D_FEAT))[lane]);
        const float ww = __int_as_float(b.y);
        acc.x = fmaf(hv.x, ww, acc.x);
        acc.y = fmaf(hv.y, ww, acc.y);
    }
    const float inv = 1.0f / fmaxf((float)cnt, 1.0f);
    float2* orow = (float2*)(out + (size_t)n * 2 * D_FEAT + D_FEAT);
    orow[lane] = make_float2(acc.x * inv, acc.y * inv);
}

__global__ void __launch_bounds__(256) overflow_kernel(
    const __half* __restrict__ hb, const float* __restrict__ w,
    const int* __restrict__ src, const int* __restrict__ dst,
    const int* __restrict__ count, const int* __restrict__ ovf_count,
    const int* __restrict__ ovf_list, float* __restrict__ out)
{
    const int novf = *ovf_count;
    if (novf == 0) return;
    const int lane  = threadIdx.x & 63;
    const int wave  = (blockIdx.x * blockDim.x + threadIdx.x) >> 6;
    const int nwave = (gridDim.x * blockDim.x) >> 6;
    for (int idx = wave; idx < novf; idx += nwave) {
        const int e = ovf_list[idx];
        const int s = src[e];
        const int d = dst[e];
        const float scale = w[e] / fmaxf((float)count[d], 1.0f);
        const float2 hv = __half22float2(((const __half2*)(hb + (size_t)s * D_FEAT))[lane]);
        float* od = out + (size_t)d * 2 * D_FEAT + D_FEAT + (lane << 1);
        atomicAdd(od,     hv.x * scale);
        atomicAdd(od + 1, hv.y * scale);
    }
}

// ---------------- tier-3 fallback (exact f32 atomic) ----------------

__global__ void __launch_bounds__(256) edge_scatter_kernel(
    const float* __restrict__ h, const float* __restrict__ w,
    const int* __restrict__ src, const int* __restrict__ dst,
    float* __restrict__ out, float* __restrict__ deg, int n_edges)
{
    const int lane  = threadIdx.x & 63;
    const int wave  = (blockIdx.x * blockDim.x + threadIdx.x) >> 6;
    const int nwave = (gridDim.x * blockDim.x) >> 6;
    for (int e = wave; e < n_edges; e += nwave) {
        const int   s  = src[e];
        const int   d  = dst[e];
        const float we = w[e];
        const float2 hv = ((const float2*)(h + (size_t)s * D_FEAT))[lane];
        float* od = out + (size_t)d * (2 * D_FEAT) + D_FEAT + (lane << 1);
        atomicAdd(od,     hv.x * we);
        atomicAdd(od + 1, hv.y * we);
        if (lane == 0) atomicAdd(deg + d, 1.0f);
    }
}

__global__ void __launch_bounds__(256) finalize_kernel(
    const float* __restrict__ h, const float* __restrict__ deg,
    float* __restrict__ out, int n_nodes)
{
    int i = blockIdx.x * blockDim.x + threadIdx.x;
    const int total  = n_nodes * 32;
    const int stride = gridDim.x * blockDim.x;
    for (; i < total; i += stride) {
        const int n = i >> 5;
        const int q = i & 31;
        const float4 hv = ((const float4*)(h + (size_t)n * D_FEAT))[q];
        ((float4*)(out + (size_t)n * 2 * D_FEAT))[q] = hv;
        const float inv = 1.0f / fmaxf(deg[n], 1.0f);
        float4* ap = ((float4*)(out + (size_t)n * 2 * D_FEAT + D_FEAT)) + q;
        float4 a = *ap;
        a.x *= inv; a.y *= inv; a.z *= inv; a.w *= inv;
        *ap = a;
    }
}

// ---------------- launch ----------------

extern "C" void kernel_launch(void* const* d_in, const int* in_sizes, int n_in,
                              void* d_out, int out_size, void* d_ws, size_t ws_size,
                              hipStream_t stream) {
    const float* h   = (const float*)d_in[0];
    const float* w   = (const float*)d_in[1];
    const int*   src = (const int*)d_in[2];
    const int*   dst = (const int*)d_in[3];
    float* out = (float*)d_out;

    const int n_edges = in_sizes[1];
    const int n_nodes = in_sizes[0] / D_FEAT;
    const int n_hel   = in_sizes[0];                      // N * 128
    const int NB      = (n_nodes + NPB - 1) >> SHIFT;     // buckets

    // Tier-1 ws layout: bcur[NBMAX] | buck[NB*CAPB] int2 | hbt[n_hel] half (4 sliced planes)
    const size_t bcur_b = NBMAX * sizeof(int);
    const size_t bk_b   = (size_t)NB * CAPB * sizeof(int2);
    const size_t hb_b   = (size_t)n_hel * sizeof(__half);
    const size_t need1  = bcur_b + bk_b + hb_b;

    // Tier-2 ws layout: count[n_nodes]+ovf | bins[n_nodes*CAP] int2 | ovf_list[n_edges] | hb
    const size_t t2_count_b = (size_t)(n_nodes + 16) * sizeof(int);
    const size_t t2_bins_b  = (size_t)n_nodes * CAP * sizeof(int2);
    const size_t t2_ovf_b   = (size_t)n_edges * sizeof(int);
    const size_t need2      = t2_count_b + t2_bins_b + t2_ovf_b + hb_b;

    // D_FEAT=128 assumed by the 4x32 slicing; guard for safety.
    if (ws_size >= need1 && NB <= NBMAX && (in_sizes[0] % D_FEAT) == 0) {
        char* p = (char*)d_ws;
        int*    bcur = (int*)p;      p += bcur_b;
        int2*   buck = (int2*)p;     p += bk_b;
        __half* hbt  = (__half*)p;

        const int fill_blocks = (n_edges + 256 * EPT - 1) / (256 * EPT);
        (void)hipMemsetAsync(bcur, 0, bcur_b, stream);
        fused_cast_bucket_kernel<<<fill_blocks + CAST_BLOCKS, 256, 0, stream>>>(
            h, hbt, out, n_hel, n_nodes, w, src, dst, bcur, buck, n_edges, fill_blocks, NB);
        bucket_gather_kernel<<<NB, 1024, 0, stream>>>(bcur, buck, hbt, out, n_nodes);
    } else if (ws_size >= need2) {
        int*    count     = (int*)d_ws;
        int*    ovf_count = count + n_nodes;
        int2*   bins      = (int2*)((char*)d_ws + t2_count_b);
        int*    ovf_list  = (int*)((char*)d_ws + t2_count_b + t2_bins_b);
        __half* hb        = (__half*)((char*)d_ws + t2_count_b + t2_bins_b + t2_ovf_b);

        (void)hipMemsetAsync(count, 0, t2_count_b, stream);
        fused_cast_fill_kernel<<<T2_CAST_BLOCKS + T2_FILL_BLOCKS, 256, 0, stream>>>(
            h, hb, out, n_hel, w, src, dst, count, ovf_count, ovf_list, bins, n_edges);
        t2_gather_kernel<<<(n_nodes + 3) / 4, 256, 0, stream>>>(hb, count, bins, out, n_nodes);
        overflow_kernel<<<64, 256, 0, stream>>>(hb, w, src, dst, count, ovf_count,
                                                ovf_list, out);
    } else {
        float* deg = (float*)d_ws;
        (void)hipMemsetAsync(out, 0, (size_t)out_size * sizeof(float), stream);
        (void)hipMemsetAsync(deg, 0, (size_t)n_nodes * sizeof(float), stream);
        edge_scatter_kernel<<<2048, 256, 0, stream>>>(h, w, src, dst, out, deg, n_edges);
        finalize_kernel<<<2048, 256, 0, stream>>>(h, deg, out, n_nodes);
    }
}

// Round 18
// 65.971 us; speedup vs baseline: 1.4326x; 1.4326x over previous
//
#include <hip/hip_runtime.h>
#include <hip/hip_fp16.h>

#define D_FEAT 128
#define SHIFT 6          // nodes per bucket = 64
#define NPB   64         // nodes per bucket
#define CAPB  1536       // bucket capacity (mean ~1023, sigma ~32 -> +16 sigma)
#define NBMAX 1024       // max buckets supported by phase-A LDS arrays
#define EPT   8          // edges per thread in phase A
#define CAST_BLOCKS 1536
#define GT    512        // bucket_gather block size (4 blocks/CU -> full occupancy)

// ---------------- fast path: LDS-bucketed scatter + in-LDS CSR + fp16 gather ----------------

// Phase A (fused): fill role buckets edges via LDS aggregation (NB up to 1024);
// cast role streams h -> fp16 mirror + exact f32 copy into out[:,0:128].
__global__ void __launch_bounds__(256) fused_cast_bucket_kernel(
    const float* __restrict__ h, __half* __restrict__ hb,
    float* __restrict__ out, int n_elems,
    const float* __restrict__ w, const int* __restrict__ src,
    const int* __restrict__ dst,
    int* __restrict__ bcur, int2* __restrict__ buck, int n_edges,
    int fill_blocks, int nb)
{
    __shared__ int lcnt[NBMAX];
    __shared__ int lbase[NBMAX];
    __shared__ int lpos[NBMAX];
    if ((int)blockIdx.x < fill_blocks) {
        const int t  = threadIdx.x;
        const int cb = blockIdx.x * (256 * EPT);
        for (int bb = t; bb < NBMAX; bb += 256) { lcnt[bb] = 0; lpos[bb] = 0; }
        __syncthreads();
        int ed[EPT], es[EPT]; float ew[EPT];
#pragma unroll
        for (int j = 0; j < EPT; ++j) {
            const int e = cb + j * 256 + t;
            if (e < n_edges) {
                ed[j] = dst[e]; es[j] = src[e]; ew[j] = w[e];
                atomicAdd(&lcnt[ed[j] >> SHIFT], 1);
            } else ed[j] = -1;
        }
        __syncthreads();
        for (int bb = t; bb < nb; bb += 256) {
            const int c = lcnt[bb];
            lbase[bb] = c ? atomicAdd(&bcur[bb], c) : 0;
        }
        __syncthreads();
#pragma unroll
        for (int j = 0; j < EPT; ++j) {
            if (ed[j] >= 0) {
                const int b   = ed[j] >> SHIFT;
                const unsigned lid = (unsigned)(ed[j] & (NPB - 1));
                const int p   = atomicAdd(&lpos[b], 1);
                const int gp  = lbase[b] + p;
                if (gp < CAPB)   // +16 sigma; statistically impossible, guard anyway
                    buck[(size_t)b * CAPB + gp] =
                        make_int2((int)((lid << 24) | (unsigned)es[j]), __float_as_int(ew[j]));
            }
        }
    } else {
        const int t      = (blockIdx.x - fill_blocks) * 256 + threadIdx.x;
        const int stride = CAST_BLOCKS * 256;
        const int n4     = n_elems >> 2;
        for (int i = t; i < n4; i += stride) {
            const float4 v = ((const float4*)h)[i];
            ((__half2*)hb)[2 * i]     = __float22half2_rn(make_float2(v.x, v.y));
            ((__half2*)hb)[2 * i + 1] = __float22half2_rn(make_float2(v.z, v.w));
            const int n = i >> 5;
            const int q = i & 31;
            ((float4*)(out + (size_t)n * 2 * D_FEAT))[q] = v;   // cols 0..127
        }
    }
}

// Merged phase B + gather: one 512-thread block per bucket (~25KB LDS ->
// 4 blocks/CU, 32 waves/CU, and 782 blocks fit one balanced dispatch wave).
// Stage bucket edges in LDS -> count/scan/permute in LDS -> 8 waves gather
// the bucket's 64 nodes from the LDS edge list (full 256B row loads, MLP-8).
__global__ void __launch_bounds__(GT) bucket_gather_kernel(
    const int* __restrict__ bcur, const int2* __restrict__ buck,
    const __half* __restrict__ hb, float* __restrict__ out, int n_nodes)
{
    __shared__ int2 ebuf[CAPB];    // 12KB raw bucket edges
    __shared__ int2 ebuf2[CAPB];   // 12KB node-ordered edges
    __shared__ int  ncnt[NPB];
    __shared__ int  sst[NPB];
    __shared__ int  ncur[NPB];
    const int b = blockIdx.x;
    const int t = threadIdx.x;
    const size_t base = (size_t)b * CAPB;
    int cnt = bcur[b]; if (cnt > CAPB) cnt = CAPB;

    if (t < NPB) ncnt[t] = 0;
    __syncthreads();
    // stage + per-node count
    for (int i = t; i < cnt; i += GT) {
        const int2 e = buck[base + i];
        ebuf[i] = e;
        atomicAdd(&ncnt[((unsigned)e.x) >> 24], 1);
    }
    __syncthreads();
    // exclusive scan over NPB node counts (uniform barriers across all threads)
    int v = 0;
    if (t < NPB) { v = ncnt[t]; sst[t] = v; }
    __syncthreads();
    for (int o = 1; o < NPB; o <<= 1) {
        int x = 0;
        if (t < NPB && t >= o) x = sst[t - o];
        __syncthreads();
        if (t < NPB) sst[t] += x;
        __syncthreads();
    }
    if (t < NPB) { const int st = sst[t] - v; sst[t] = st; ncur[t] = st; }
    __syncthreads();
    // permute into node order (LDS atomic cursors)
    for (int i = t; i < cnt; i += GT) {
        const int2 e = ebuf[i];
        const unsigned ex = (unsigned)e.x;
        const int lid = (int)(ex >> 24);
        const int p = atomicAdd(&ncur[lid], 1);
        ebuf2[p] = make_int2((int)(ex & 0xFFFFFFu), e.y);
    }
    __syncthreads();

    // gather: wave wv handles nodes wv, wv+8, ... within the bucket
    const int lane = t & 63;
    const int wv   = t >> 6;

#define HROW(s) __half22float2(((const __half2*)(hb + (size_t)(s) * D_FEAT))[lane])

    for (int ln = wv; ln < NPB; ln += GT / 64) {
        const int n = b * NPB + ln;
        if (n >= n_nodes) continue;
        const int st = sst[ln];
        const int c  = ncnt[ln];
        float2 acc = make_float2(0.0f, 0.0f);
        int k = 0;
        for (; k + 8 <= c; k += 8) {
            const int2 b0 = ebuf2[st + k + 0], b1 = ebuf2[st + k + 1];
            const int2 b2 = ebuf2[st + k + 2], b3 = ebuf2[st + k + 3];
            const int2 b4 = ebuf2[st + k + 4], b5 = ebuf2[st + k + 5];
            const int2 b6 = ebuf2[st + k + 6], b7 = ebuf2[st + k + 7];
            const float2 h0 = HROW(b0.x);
            const float2 h1 = HROW(b1.x);
            const float2 h2 = HROW(b2.x);
            const float2 h3 = HROW(b3.x);
            const float2 h4 = HROW(b4.x);
            const float2 h5 = HROW(b5.x);
            const float2 h6 = HROW(b6.x);
            const float2 h7 = HROW(b7.x);
            const float w0 = __int_as_float(b0.y), w1 = __int_as_float(b1.y);
            const float w2 = __int_as_float(b2.y), w3 = __int_as_float(b3.y);
            const float w4 = __int_as_float(b4.y), w5 = __int_as_float(b5.y);
            const float w6 = __int_as_float(b6.y), w7 = __int_as_float(b7.y);
            acc.x = fmaf(h0.x, w0, acc.x); acc.y = fmaf(h0.y, w0, acc.y);
            acc.x = fmaf(h1.x, w1, acc.x); acc.y = fmaf(h1.y, w1, acc.y);
            acc.x = fmaf(h2.x, w2, acc.x); acc.y = fmaf(h2.y, w2, acc.y);
            acc.x = fmaf(h3.x, w3, acc.x); acc.y = fmaf(h3.y, w3, acc.y);
            acc.x = fmaf(h4.x, w4, acc.x); acc.y = fmaf(h4.y, w4, acc.y);
            acc.x = fmaf(h5.x, w5, acc.x); acc.y = fmaf(h5.y, w5, acc.y);
            acc.x = fmaf(h6.x, w6, acc.x); acc.y = fmaf(h6.y, w6, acc.y);
            acc.x = fmaf(h7.x, w7, acc.x); acc.y = fmaf(h7.y, w7, acc.y);
        }
        for (; k < c; ++k) {
            const int2 e = ebuf2[st + k];
            const float ww = __int_as_float(e.y);
            const float2 hv = HROW(e.x);
            acc.x = fmaf(hv.x, ww, acc.x);
            acc.y = fmaf(hv.y, ww, acc.y);
        }
        const float inv = 1.0f / fmaxf((float)c, 1.0f);
        float2* orow = (float2*)(out + (size_t)n * 2 * D_FEAT + D_FEAT);
        orow[lane] = make_float2(acc.x * inv, acc.y * inv);   // cols 128..255
    }
#undef HROW
}

// ---------------- tier-2 path (round-12 measured: fused cast+fill, CAP bins) ----------------

#define CAP 32
#define T2_CAST_BLOCKS 512
#define T2_FILL_BLOCKS 2048

__global__ void __launch_bounds__(256) fused_cast_fill_kernel(
    const float* __restrict__ h, __half* __restrict__ hb,
    float* __restrict__ out, int n_elems,
    const float* __restrict__ w, const int* __restrict__ src,
    const int* __restrict__ dst,
    int* __restrict__ count, int* __restrict__ ovf_count,
    int* __restrict__ ovf_list, int2* __restrict__ bins, int n_edges)
{
    if (blockIdx.x < T2_CAST_BLOCKS) {
        const int t      = blockIdx.x * blockDim.x + threadIdx.x;
        const int stride = T2_CAST_BLOCKS * blockDim.x;
        const int n4     = n_elems >> 2;
        for (int i = t; i < n4; i += stride) {
            const float4 v = ((const float4*)h)[i];
            ((__half2*)hb)[2 * i]     = __float22half2_rn(make_float2(v.x, v.y));
            ((__half2*)hb)[2 * i + 1] = __float22half2_rn(make_float2(v.z, v.w));
            const int n = i >> 5;
            const int q = i & 31;
            ((float4*)(out + (size_t)n * 2 * D_FEAT))[q] = v;
        }
    } else {
        const int t      = (blockIdx.x - T2_CAST_BLOCKS) * blockDim.x + threadIdx.x;
        const int stride = T2_FILL_BLOCKS * blockDim.x;
        for (int e = t; e < n_edges; e += stride) {
            const int d = dst[e];
            const int pos = atomicAdd(&count[d], 1);
            if (pos < CAP) {
                bins[(size_t)d * CAP + pos] = make_int2(src[e], __float_as_int(w[e]));
            } else {
                const int o = atomicAdd(ovf_count, 1);
                ovf_list[o] = e;
            }
        }
    }
}

__global__ void __launch_bounds__(256) t2_gather_kernel(
    const __half* __restrict__ hb, const int* __restrict__ count,
    const int2* __restrict__ bins, float* __restrict__ out, int n_nodes)
{
    const int lane = threadIdx.x & 63;
    const int wave = (blockIdx.x * blockDim.x + threadIdx.x) >> 6;
    if (wave >= n_nodes) return;
    const int n   = wave;
    const int cnt = count[n];
    const int c   = cnt < CAP ? cnt : CAP;
    float2 acc = make_float2(0.0f, 0.0f);
    const int2* bp = bins + (size_t)n * CAP;
    for (int k = 0; k < c; ++k) {
        const int2 b = bp[k];
        const float2 hv = __half22float2(((const __half2*)(hb + (size_t)b.x * D_FEAT))[lane]);
        const float ww = __int_as_float(b.y);
        acc.x = fmaf(hv.x, ww, acc.x);
        acc.y = fmaf(hv.y, ww, acc.y);
    }
    const float inv = 1.0f / fmaxf((float)cnt, 1.0f);
    float2* orow = (float2*)(out + (size_t)n * 2 * D_FEAT + D_FEAT);
    orow[lane] = make_float2(acc.x * inv, acc.y * inv);
}

__global__ void __launch_bounds__(256) overflow_kernel(
    const __half* __restrict__ hb, const float* __restrict__ w,
    const int* __restrict__ src, const int* __restrict__ dst,
    const int* __restrict__ count, const int* __restrict__ ovf_count,
    const int* __restrict__ ovf_list, float* __restrict__ out)
{
    const int novf = *ovf_count;
    if (novf == 0) return;
    const int lane  = threadIdx.x & 63;
    const int wave  = (blockIdx.x * blockDim.x + threadIdx.x) >> 6;
    const int nwave = (gridDim.x * blockDim.x) >> 6;
    for (int idx = wave; idx < novf; idx += nwave) {
        const int e = ovf_list[idx];
        const int s = src[e];
        const int d = dst[e];
        const float scale = w[e] / fmaxf((float)count[d], 1.0f);
        const float2 hv = __half22float2(((const __half2*)(hb + (size_t)s * D_FEAT))[lane]);
        float* od = out + (size_t)d * 2 * D_FEAT + D_FEAT + (lane << 1);
        atomicAdd(od,     hv.x * scale);
        atomicAdd(od + 1, hv.y * scale);
    }
}

// ---------------- tier-3 fallback (exact f32 atomic) ----------------

__global__ void __launch_bounds__(256) edge_scatter_kernel(
    const float* __restrict__ h, const float* __restrict__ w,
    const int* __restrict__ src, const int* __restrict__ dst,
    float* __restrict__ out, float* __restrict__ deg, int n_edges)
{
    const int lane  = threadIdx.x & 63;
    const int wave  = (blockIdx.x * blockDim.x + threadIdx.x) >> 6;
    const int nwave = (gridDim.x * blockDim.x) >> 6;
    for (int e = wave; e < n_edges; e += nwave) {
        const int   s  = src[e];
        const int   d  = dst[e];
        const float we = w[e];
        const float2 hv = ((const float2*)(h + (size_t)s * D_FEAT))[lane];
        float* od = out + (size_t)d * (2 * D_FEAT) + D_FEAT + (lane << 1);
        atomicAdd(od,     hv.x * we);
        atomicAdd(od + 1, hv.y * we);
        if (lane == 0) atomicAdd(deg + d, 1.0f);
    }
}

__global__ void __launch_bounds__(256) finalize_kernel(
    const float* __restrict__ h, const float* __restrict__ deg,
    float* __restrict__ out, int n_nodes)
{
    int i = blockIdx.x * blockDim.x + threadIdx.x;
    const int total  = n_nodes * 32;
    const int stride = gridDim.x * blockDim.x;
    for (; i < total; i += stride) {
        const int n = i >> 5;
        const int q = i & 31;
        const float4 hv = ((const float4*)(h + (size_t)n * D_FEAT))[q];
        ((float4*)(out + (size_t)n * 2 * D_FEAT))[q] = hv;
        const float inv = 1.0f / fmaxf(deg[n], 1.0f);
        float4* ap = ((float4*)(out + (size_t)n * 2 * D_FEAT + D_FEAT)) + q;
        float4 a = *ap;
        a.x *= inv; a.y *= inv; a.z *= inv; a.w *= inv;
        *ap = a;
    }
}

// ---------------- launch ----------------

extern "C" void kernel_launch(void* const* d_in, const int* in_sizes, int n_in,
                              void* d_out, int out_size, void* d_ws, size_t ws_size,
                              hipStream_t stream) {
    const float* h   = (const float*)d_in[0];
    const float* w   = (const float*)d_in[1];
    const int*   src = (const int*)d_in[2];
    const int*   dst = (const int*)d_in[3];
    float* out = (float*)d_out;

    const int n_edges = in_sizes[1];
    const int n_nodes = in_sizes[0] / D_FEAT;
    const int n_hel   = in_sizes[0];                      // N * 128
    const int NB      = (n_nodes + NPB - 1) >> SHIFT;     // buckets

    // Tier-1 ws layout: bcur[NBMAX] | buck[NB*CAPB] int2 | hb[n_hel] half
    const size_t bcur_b = NBMAX * sizeof(int);
    const size_t bk_b   = (size_t)NB * CAPB * sizeof(int2);
    const size_t hb_b   = (size_t)n_hel * sizeof(__half);
    const size_t need1  = bcur_b + bk_b + hb_b;

    // Tier-2 ws layout: count[n_nodes]+ovf | bins[n_nodes*CAP] int2 | ovf_list[n_edges] | hb
    const size_t t2_count_b = (size_t)(n_nodes + 16) * sizeof(int);
    const size_t t2_bins_b  = (size_t)n_nodes * CAP * sizeof(int2);
    const size_t t2_ovf_b   = (size_t)n_edges * sizeof(int);
    const size_t need2      = t2_count_b + t2_bins_b + t2_ovf_b + hb_b;

    if (ws_size >= need1 && NB <= NBMAX) {
        char* p = (char*)d_ws;
        int*    bcur = (int*)p;      p += bcur_b;
        int2*   buck = (int2*)p;     p += bk_b;
        __half* hb   = (__half*)p;

        const int fill_blocks = (n_edges + 256 * EPT - 1) / (256 * EPT);
        (void)hipMemsetAsync(bcur, 0, bcur_b, stream);
        fused_cast_bucket_kernel<<<fill_blocks + CAST_BLOCKS, 256, 0, stream>>>(
            h, hb, out, n_hel, w, src, dst, bcur, buck, n_edges, fill_blocks, NB);
        bucket_gather_kernel<<<NB, GT, 0, stream>>>(bcur, buck, hb, out, n_nodes);
    } else if (ws_size >= need2) {
        int*    count     = (int*)d_ws;
        int*    ovf_count = count + n_nodes;
        int2*   bins      = (int2*)((char*)d_ws + t2_count_b);
        int*    ovf_list  = (int*)((char*)d_ws + t2_count_b + t2_bins_b);
        __half* hb        = (__half*)((char*)d_ws + t2_count_b + t2_bins_b + t2_ovf_b);

        (void)hipMemsetAsync(count, 0, t2_count_b, stream);
        fused_cast_fill_kernel<<<T2_CAST_BLOCKS + T2_FILL_BLOCKS, 256, 0, stream>>>(
            h, hb, out, n_hel, w, src, dst, count, ovf_count, ovf_list, bins, n_edges);
        t2_gather_kernel<<<(n_nodes + 3) / 4, 256, 0, stream>>>(hb, count, bins, out, n_nodes);
        overflow_kernel<<<64, 256, 0, stream>>>(hb, w, src, dst, count, ovf_count,
                                                ovf_list, out);
    } else {
        float* deg = (float*)d_ws;
        (void)hipMemsetAsync(out, 0, (size_t)out_size * sizeof(float), stream);
        (void)hipMemsetAsync(deg, 0, (size_t)n_nodes * sizeof(float), stream);
        edge_scatter_kernel<<<2048, 256, 0, stream>>>(h, w, src, dst, out, deg, n_edges);
        finalize_kernel<<<2048, 256, 0, stream>>>(h, deg, out, n_nodes);
    }
}

// Round 19
// 65.905 us; speedup vs baseline: 1.4341x; 1.0010x over previous
//
#include <hip/hip_runtime.h>
#include <hip/hip_fp16.h>

#define D_FEAT 128
#define SHIFT 6          // nodes per bucket = 64
#define NPB   64         // nodes per bucket
#define CAPB  1536       // bucket capacity (mean ~1023, sigma ~32 -> +16 sigma)
#define NBMAX 1024       // max buckets supported by phase-A LDS arrays
#define EPT   8          // edges per thread in phase A
#define CAST_BLOCKS 1536
#define GT    512        // bucket_gather block size (4 blocks/CU -> full occupancy)

// Native-vector nontemporal stores (HIP_vector_type is rejected by the builtin).
typedef float f32x4_t __attribute__((ext_vector_type(4)));
typedef float f32x2_t __attribute__((ext_vector_type(2)));
__device__ __forceinline__ void nt_store4(const float4& v, float* p) {
    f32x4_t x; x.x = v.x; x.y = v.y; x.z = v.z; x.w = v.w;
    __builtin_nontemporal_store(x, (f32x4_t*)p);
}
__device__ __forceinline__ void nt_store2(const float2& v, float* p) {
    f32x2_t x; x.x = v.x; x.y = v.y;
    __builtin_nontemporal_store(x, (f32x2_t*)p);
}

// ---------------- fast path: LDS-bucketed scatter + in-LDS CSR + fp16 gather ----------------

// Phase A (fused): fill role buckets edges via LDS aggregation (NB up to 1024);
// cast role streams h -> fp16 mirror + exact f32 copy into out[:,0:128] (NT).
__global__ void __launch_bounds__(256) fused_cast_bucket_kernel(
    const float* __restrict__ h, __half* __restrict__ hb,
    float* __restrict__ out, int n_elems,
    const float* __restrict__ w, const int* __restrict__ src,
    const int* __restrict__ dst,
    int* __restrict__ bcur, int2* __restrict__ buck, int n_edges,
    int fill_blocks, int nb)
{
    __shared__ int lcnt[NBMAX];
    __shared__ int lbase[NBMAX];
    __shared__ int lpos[NBMAX];
    if ((int)blockIdx.x < fill_blocks) {
        const int t  = threadIdx.x;
        const int cb = blockIdx.x * (256 * EPT);
        for (int bb = t; bb < NBMAX; bb += 256) { lcnt[bb] = 0; lpos[bb] = 0; }
        __syncthreads();
        int ed[EPT], es[EPT]; float ew[EPT];
#pragma unroll
        for (int j = 0; j < EPT; ++j) {
            const int e = cb + j * 256 + t;
            if (e < n_edges) {
                ed[j] = dst[e]; es[j] = src[e]; ew[j] = w[e];
                atomicAdd(&lcnt[ed[j] >> SHIFT], 1);
            } else ed[j] = -1;
        }
        __syncthreads();
        for (int bb = t; bb < nb; bb += 256) {
            const int c = lcnt[bb];
            lbase[bb] = c ? atomicAdd(&bcur[bb], c) : 0;
        }
        __syncthreads();
#pragma unroll
        for (int j = 0; j < EPT; ++j) {
            if (ed[j] >= 0) {
                const int b   = ed[j] >> SHIFT;
                const unsigned lid = (unsigned)(ed[j] & (NPB - 1));
                const int p   = atomicAdd(&lpos[b], 1);
                const int gp  = lbase[b] + p;
                if (gp < CAPB)   // +16 sigma; statistically impossible, guard anyway
                    buck[(size_t)b * CAPB + gp] =
                        make_int2((int)((lid << 24) | (unsigned)es[j]), __float_as_int(ew[j]));
            }
        }
    } else {
        const int t      = (blockIdx.x - fill_blocks) * 256 + threadIdx.x;
        const int stride = CAST_BLOCKS * 256;
        const int n4     = n_elems >> 2;
        for (int i = t; i < n4; i += stride) {
            const float4 v = ((const float4*)h)[i];
            ((__half2*)hb)[2 * i]     = __float22half2_rn(make_float2(v.x, v.y));
            ((__half2*)hb)[2 * i + 1] = __float22half2_rn(make_float2(v.z, v.w));
            const int n = i >> 5;
            const int q = i & 31;
            nt_store4(v, out + (size_t)n * 2 * D_FEAT + 4 * q);   // cols 0..127, NT
        }
    }
}

// Merged phase B + gather: one 512-thread block per bucket (~25KB LDS ->
// 4 blocks/CU, 782 blocks in one balanced dispatch wave).
// Stage bucket edges in LDS -> count/scan/permute in LDS -> 8 waves gather
// the bucket's 64 nodes from the LDS edge list. Out stores are NONTEMPORAL
// so the 25.6MB output stream doesn't evict hb from per-XCD L2.
__global__ void __launch_bounds__(GT) bucket_gather_kernel(
    const int* __restrict__ bcur, const int2* __restrict__ buck,
    const __half* __restrict__ hb, float* __restrict__ out, int n_nodes)
{
    __shared__ int2 ebuf[CAPB];    // 12KB raw bucket edges
    __shared__ int2 ebuf2[CAPB];   // 12KB node-ordered edges
    __shared__ int  ncnt[NPB];
    __shared__ int  sst[NPB];
    __shared__ int  ncur[NPB];
    const int b = blockIdx.x;
    const int t = threadIdx.x;
    const size_t base = (size_t)b * CAPB;
    int cnt = bcur[b]; if (cnt > CAPB) cnt = CAPB;

    if (t < NPB) ncnt[t] = 0;
    __syncthreads();
    for (int i = t; i < cnt; i += GT) {
        const int2 e = buck[base + i];
        ebuf[i] = e;
        atomicAdd(&ncnt[((unsigned)e.x) >> 24], 1);
    }
    __syncthreads();
    int v = 0;
    if (t < NPB) { v = ncnt[t]; sst[t] = v; }
    __syncthreads();
    for (int o = 1; o < NPB; o <<= 1) {
        int x = 0;
        if (t < NPB && t >= o) x = sst[t - o];
        __syncthreads();
        if (t < NPB) sst[t] += x;
        __syncthreads();
    }
    if (t < NPB) { const int st = sst[t] - v; sst[t] = st; ncur[t] = st; }
    __syncthreads();
    for (int i = t; i < cnt; i += GT) {
        const int2 e = ebuf[i];
        const unsigned ex = (unsigned)e.x;
        const int lid = (int)(ex >> 24);
        const int p = atomicAdd(&ncur[lid], 1);
        ebuf2[p] = make_int2((int)(ex & 0xFFFFFFu), e.y);
    }
    __syncthreads();

    const int lane = t & 63;
    const int wv   = t >> 6;

#define HROW(s) __half22float2(((const __half2*)(hb + (size_t)(s) * D_FEAT))[lane])

    for (int ln = wv; ln < NPB; ln += GT / 64) {
        const int n = b * NPB + ln;
        if (n >= n_nodes) continue;
        const int st = sst[ln];
        const int c  = ncnt[ln];
        float2 acc = make_float2(0.0f, 0.0f);
        int k = 0;
        for (; k + 8 <= c; k += 8) {
            const int2 b0 = ebuf2[st + k + 0], b1 = ebuf2[st + k + 1];
            const int2 b2 = ebuf2[st + k + 2], b3 = ebuf2[st + k + 3];
            const int2 b4 = ebuf2[st + k + 4], b5 = ebuf2[st + k + 5];
            const int2 b6 = ebuf2[st + k + 6], b7 = ebuf2[st + k + 7];
            const float2 h0 = HROW(b0.x);
            const float2 h1 = HROW(b1.x);
            const float2 h2 = HROW(b2.x);
            const float2 h3 = HROW(b3.x);
            const float2 h4 = HROW(b4.x);
            const float2 h5 = HROW(b5.x);
            const float2 h6 = HROW(b6.x);
            const float2 h7 = HROW(b7.x);
            const float w0 = __int_as_float(b0.y), w1 = __int_as_float(b1.y);
            const float w2 = __int_as_float(b2.y), w3 = __int_as_float(b3.y);
            const float w4 = __int_as_float(b4.y), w5 = __int_as_float(b5.y);
            const float w6 = __int_as_float(b6.y), w7 = __int_as_float(b7.y);
            acc.x = fmaf(h0.x, w0, acc.x); acc.y = fmaf(h0.y, w0, acc.y);
            acc.x = fmaf(h1.x, w1, acc.x); acc.y = fmaf(h1.y, w1, acc.y);
            acc.x = fmaf(h2.x, w2, acc.x); acc.y = fmaf(h2.y, w2, acc.y);
            acc.x = fmaf(h3.x, w3, acc.x); acc.y = fmaf(h3.y, w3, acc.y);
            acc.x = fmaf(h4.x, w4, acc.x); acc.y = fmaf(h4.y, w4, acc.y);
            acc.x = fmaf(h5.x, w5, acc.x); acc.y = fmaf(h5.y, w5, acc.y);
            acc.x = fmaf(h6.x, w6, acc.x); acc.y = fmaf(h6.y, w6, acc.y);
            acc.x = fmaf(h7.x, w7, acc.x); acc.y = fmaf(h7.y, w7, acc.y);
        }
        for (; k < c; ++k) {
            const int2 e = ebuf2[st + k];
            const float ww = __int_as_float(e.y);
            const float2 hv = HROW(e.x);
            acc.x = fmaf(hv.x, ww, acc.x);
            acc.y = fmaf(hv.y, ww, acc.y);
        }
        const float inv = 1.0f / fmaxf((float)c, 1.0f);
        nt_store2(make_float2(acc.x * inv, acc.y * inv),
                  out + (size_t)n * 2 * D_FEAT + D_FEAT + 2 * lane);  // cols 128..255, NT
    }
#undef HROW
}

// ---------------- tier-2 path (round-12 measured: fused cast+fill, CAP bins) ----------------

#define CAP 32
#define T2_CAST_BLOCKS 512
#define T2_FILL_BLOCKS 2048

__global__ void __launch_bounds__(256) fused_cast_fill_kernel(
    const float* __restrict__ h, __half* __restrict__ hb,
    float* __restrict__ out, int n_elems,
    const float* __restrict__ w, const int* __restrict__ src,
    const int* __restrict__ dst,
    int* __restrict__ count, int* __restrict__ ovf_count,
    int* __restrict__ ovf_list, int2* __restrict__ bins, int n_edges)
{
    if (blockIdx.x < T2_CAST_BLOCKS) {
        const int t      = blockIdx.x * blockDim.x + threadIdx.x;
        const int stride = T2_CAST_BLOCKS * blockDim.x;
        const int n4     = n_elems >> 2;
        for (int i = t; i < n4; i += stride) {
            const float4 v = ((const float4*)h)[i];
            ((__half2*)hb)[2 * i]     = __float22half2_rn(make_float2(v.x, v.y));
            ((__half2*)hb)[2 * i + 1] = __float22half2_rn(make_float2(v.z, v.w));
            const int n = i >> 5;
            const int q = i & 31;
            ((float4*)(out + (size_t)n * 2 * D_FEAT))[q] = v;
        }
    } else {
        const int t      = (blockIdx.x - T2_CAST_BLOCKS) * blockDim.x + threadIdx.x;
        const int stride = T2_FILL_BLOCKS * blockDim.x;
        for (int e = t; e < n_edges; e += stride) {
            const int d = dst[e];
            const int pos = atomicAdd(&count[d], 1);
            if (pos < CAP) {
                bins[(size_t)d * CAP + pos] = make_int2(src[e], __float_as_int(w[e]));
            } else {
                const int o = atomicAdd(ovf_count, 1);
                ovf_list[o] = e;
            }
        }
    }
}

__global__ void __launch_bounds__(256) t2_gather_kernel(
    const __half* __restrict__ hb, const int* __restrict__ count,
    const int2* __restrict__ bins, float* __restrict__ out, int n_nodes)
{
    const int lane = threadIdx.x & 63;
    const int wave = (blockIdx.x * blockDim.x + threadIdx.x) >> 6;
    if (wave >= n_nodes) return;
    const int n   = wave;
    const int cnt = count[n];
    const int c   = cnt < CAP ? cnt : CAP;
    float2 acc = make_float2(0.0f, 0.0f);
    const int2* bp = bins + (size_t)n * CAP;
    for (int k = 0; k < c; ++k) {
        const int2 b = bp[k];
        const float2 hv = __half22float2(((const __half2*)(hb + (size_t)b.x * D_FEAT))[lane]);
        const float ww = __int_as_float(b.y);
        acc.x = fmaf(hv.x, ww, acc.x);
        acc.y = fmaf(hv.y, ww, acc.y);
    }
    const float inv = 1.0f / fmaxf((float)cnt, 1.0f);
    float2* orow = (float2*)(out + (size_t)n * 2 * D_FEAT + D_FEAT);
    orow[lane] = make_float2(acc.x * inv, acc.y * inv);
}

__global__ void __launch_bounds__(256) overflow_kernel(
    const __half* __restrict__ hb, const float* __restrict__ w,
    const int* __restrict__ src, const int* __restrict__ dst,
    const int* __restrict__ count, const int* __restrict__ ovf_count,
    const int* __restrict__ ovf_list, float* __restrict__ out)
{
    const int novf = *ovf_count;
    if (novf == 0) return;
    const int lane  = threadIdx.x & 63;
    const int wave  = (blockIdx.x * blockDim.x + threadIdx.x) >> 6;
    const int nwave = (gridDim.x * blockDim.x) >> 6;
    for (int idx = wave; idx < novf; idx += nwave) {
        const int e = ovf_list[idx];
        const int s = src[e];
        const int d = dst[e];
        const float scale = w[e] / fmaxf((float)count[d], 1.0f);
        const float2 hv = __half22float2(((const __half2*)(hb + (size_t)s * D_FEAT))[lane]);
        float* od = out + (size_t)d * 2 * D_FEAT + D_FEAT + (lane << 1);
        atomicAdd(od,     hv.x * scale);
        atomicAdd(od + 1, hv.y * scale);
    }
}

// ---------------- tier-3 fallback (exact f32 atomic) ----------------

__global__ void __launch_bounds__(256) edge_scatter_kernel(
    const float* __restrict__ h, const float* __restrict__ w,
    const int* __restrict__ src, const int* __restrict__ dst,
    float* __restrict__ out, float* __restrict__ deg, int n_edges)
{
    const int lane  = threadIdx.x & 63;
    const int wave  = (blockIdx.x * blockDim.x + threadIdx.x) >> 6;
    const int nwave = (gridDim.x * blockDim.x) >> 6;
    for (int e = wave; e < n_edges; e += nwave) {
        const int   s  = src[e];
        const int   d  = dst[e];
        const float we = w[e];
        const float2 hv = ((const float2*)(h + (size_t)s * D_FEAT))[lane];
        float* od = out + (size_t)d * (2 * D_FEAT) + D_FEAT + (lane << 1);
        atomicAdd(od,     hv.x * we);
        atomicAdd(od + 1, hv.y * we);
        if (lane == 0) atomicAdd(deg + d, 1.0f);
    }
}

__global__ void __launch_bounds__(256) finalize_kernel(
    const float* __restrict__ h, const float* __restrict__ deg,
    float* __restrict__ out, int n_nodes)
{
    int i = blockIdx.x * blockDim.x + threadIdx.x;
    const int total  = n_nodes * 32;
    const int stride = gridDim.x * blockDim.x;
    for (; i < total; i += stride) {
        const int n = i >> 5;
        const int q = i & 31;
        const float4 hv = ((const float4*)(h + (size_t)n * D_FEAT))[q];
        ((float4*)(out + (size_t)n * 2 * D_FEAT))[q] = hv;
        const float inv = 1.0f / fmaxf(deg[n], 1.0f);
        float4* ap = ((float4*)(out + (size_t)n * 2 * D_FEAT + D_FEAT)) + q;
        float4 a = *ap;
        a.x *= inv; a.y *= inv; a.z *= inv; a.w *= inv;
        *ap = a;
    }
}

// ---------------- launch ----------------

extern "C" void kernel_launch(void* const* d_in, const int* in_sizes, int n_in,
                              void* d_out, int out_size, void* d_ws, size_t ws_size,
                              hipStream_t stream) {
    const float* h   = (const float*)d_in[0];
    const float* w   = (const float*)d_in[1];
    const int*   src = (const int*)d_in[2];
    const int*   dst = (const int*)d_in[3];
    float* out = (float*)d_out;

    const int n_edges = in_sizes[1];
    const int n_nodes = in_sizes[0] / D_FEAT;
    const int n_hel   = in_sizes[0];                      // N * 128
    const int NB      = (n_nodes + NPB - 1) >> SHIFT;     // buckets

    // Tier-1 ws layout: bcur[NBMAX] | buck[NB*CAPB] int2 | hb[n_hel] half
    const size_t bcur_b = NBMAX * sizeof(int);
    const size_t bk_b   = (size_t)NB * CAPB * sizeof(int2);
    const size_t hb_b   = (size_t)n_hel * sizeof(__half);
    const size_t need1  = bcur_b + bk_b + hb_b;

    // Tier-2 ws layout: count[n_nodes]+ovf | bins[n_nodes*CAP] int2 | ovf_list[n_edges] | hb
    const size_t t2_count_b = (size_t)(n_nodes + 16) * sizeof(int);
    const size_t t2_bins_b  = (size_t)n_nodes * CAP * sizeof(int2);
    const size_t t2_ovf_b   = (size_t)n_edges * sizeof(int);
    const size_t need2      = t2_count_b + t2_bins_b + t2_ovf_b + hb_b;

    if (ws_size >= need1 && NB <= NBMAX) {
        char* p = (char*)d_ws;
        int*    bcur = (int*)p;      p += bcur_b;
        int2*   buck = (int2*)p;     p += bk_b;
        __half* hb   = (__half*)p;

        const int fill_blocks = (n_edges + 256 * EPT - 1) / (256 * EPT);
        (void)hipMemsetAsync(bcur, 0, bcur_b, stream);
        fused_cast_bucket_kernel<<<fill_blocks + CAST_BLOCKS, 256, 0, stream>>>(
            h, hb, out, n_hel, w, src, dst, bcur, buck, n_edges, fill_blocks, NB);
        bucket_gather_kernel<<<NB, GT, 0, stream>>>(bcur, buck, hb, out, n_nodes);
    } else if (ws_size >= need2) {
        int*    count     = (int*)d_ws;
        int*    ovf_count = count + n_nodes;
        int2*   bins      = (int2*)((char*)d_ws + t2_count_b);
        int*    ovf_list  = (int*)((char*)d_ws + t2_count_b + t2_bins_b);
        __half* hb        = (__half*)((char*)d_ws + t2_count_b + t2_bins_b + t2_ovf_b);

        (void)hipMemsetAsync(count, 0, t2_count_b, stream);
        fused_cast_fill_kernel<<<T2_CAST_BLOCKS + T2_FILL_BLOCKS, 256, 0, stream>>>(
            h, hb, out, n_hel, w, src, dst, count, ovf_count, ovf_list, bins, n_edges);
        t2_gather_kernel<<<(n_nodes + 3) / 4, 256, 0, stream>>>(hb, count, bins, out, n_nodes);
        overflow_kernel<<<64, 256, 0, stream>>>(hb, w, src, dst, count, ovf_count,
                                                ovf_list, out);
    } else {
        float* deg = (float*)d_ws;
        (void)hipMemsetAsync(out, 0, (size_t)out_size * sizeof(float), stream);
        (void)hipMemsetAsync(deg, 0, (size_t)n_nodes * sizeof(float), stream);
        edge_scatter_kernel<<<2048, 256, 0, stream>>>(h, w, src, dst, out, deg, n_edges);
        finalize_kernel<<<2048, 256, 0, stream>>>(h, deg, out, n_nodes);
    }
}